// Round 6
// baseline (516.481 us; speedup 1.0000x reference)
//
#include <hip/hip_runtime.h>

// ---------------------------------------------------------------------------
// RetnetBlock fp16-MFMA implementation.
// R5: fused flash-style attention — per (128 Q-rows, head) block: Q resident
//     in LDS; per 64-wide KV tile: S=Q·K^T in regs (MFMA), ×decay (per-lane
//     f32 global reads, L3-resident), S through padded LDS tile (C/D -> A
//     layout transform), PV MFMA accumulate; silu(xo) epilogue writes gated.
//     Removes G2/G3/reduce_gate, the 256 MB S round-trip and 128 MB Pg
//     round-trip. gemm_bt core unchanged from R4 (BK=64 + XOR swizzle).
// ---------------------------------------------------------------------------

typedef _Float16 f16;
typedef _Float16 f16x8 __attribute__((ext_vector_type(8)));
typedef float floatx4 __attribute__((ext_vector_type(4)));

#define EP_BIAS_F16      0
#define EP_DECAY_F16     1
#define EP_BIAS_GELU_F16 2
#define EP_PARTIAL_F32   3

template <bool F32> struct out_sel { typedef f16 T; };
template <> struct out_sel<true>   { typedef float T; };

__device__ __forceinline__ void gload_lds16(const void* g, void* s) {
    __builtin_amdgcn_global_load_lds(
        (const __attribute__((address_space(1))) unsigned int*)g,
        (__attribute__((address_space(3))) unsigned int*)s, 16, 0, 0);
}

// erf via Abramowitz-Stegun 7.1.26, |abs err| <= 1.5e-7
__device__ __forceinline__ float erf_fast(float x) {
    const float ax = fabsf(x);
    const float t  = __builtin_amdgcn_rcpf(1.f + 0.3275911f * ax);
    const float p  = t * (0.254829592f + t * (-0.284496736f + t * (1.421413741f +
                     t * (-1.453152027f + t * 1.061405429f))));
    const float r  = 1.f - p * __expf(-ax * ax);
    return copysignf(r, x);
}

// ---------------------------------------------------------------------------
// Fused attention: gated[b*1024+l, h*64+d] =
//   (sum_m (q_l . k_m) * decay[h,l,m] * v_m_d) * silu(xo[l, h*64+d])
// Block = 128 Q-rows x one (b,h). 4 waves: S-tile 128x64 (wave 64x32),
// O-tile 128x64 (wave 64x32). KV tiles of 64.
// ---------------------------------------------------------------------------
__global__ __launch_bounds__(256, 3) void attn_fused(
    const f16* __restrict__ p, const f16* __restrict__ vT,
    const float* __restrict__ decay, f16* __restrict__ gated)
{
    const int z = blockIdx.y;
    const int b = z >> 4, h = z & 15;
    const int m0 = blockIdx.x * 128;

    __shared__ __align__(16) f16 Qs[128 * 64];   // 16 KB, swizzled chunks
    __shared__ __align__(16) f16 Ks[64 * 64];    //  8 KB, swizzled
    __shared__ __align__(16) f16 Vs[64 * 64];    //  8 KB, swizzled
    __shared__ __align__(16) f16 Ss[128 * 72];   // 18 KB, padded (+8/row)

    const int t    = threadIdx.x;
    const int lane = t & 63;
    const int w    = t >> 6;
    const int quad = lane >> 4;
    const int fr   = lane & 15;
    const int wm   = (w >> 1) * 64;   // q-offset of wave
    const int wn   = (w & 1) * 32;    // kv-offset (S phase) / d-offset (PV)

    const f16*   Qg = p + (size_t)(b * 1024 + m0) * 4096 + h * 64;
    const f16*   Kg = p + (size_t)(b * 1024) * 4096 + 1024 + h * 64;
    const f16*   Vg = vT + (size_t)z * 65536;                 // [64][1024]
    const float* Dg = decay + (size_t)h * 1048576;            // [1024][1024]
    const f16*   XOg = p + (size_t)(b * 1024 + m0) * 4096 + 3072 + h * 64;

    // stage Q (128 rows x 64 f16 = 1024 16B-chunks), XOR-swizzled like gemm
#pragma unroll
    for (int i = 0; i < 4; ++i) {
        const int ci = t + i * 256;
        const int r  = ci >> 3;
        const int c  = ((ci & 7) ^ (r & 7)) * 8;
        gload_lds16(Qg + (size_t)r * 4096 + c, &Qs[ci * 8]);
    }

    floatx4 o_acc[4][2] = {};

    for (int j = 0; j < 1024; j += 64) {
        // stage K,V tiles (64x64 each = 512 chunks each)
#pragma unroll
        for (int i = 0; i < 2; ++i) {
            const int ci = t + i * 256;
            const int r  = ci >> 3;
            const int c  = ((ci & 7) ^ (r & 7)) * 8;
            gload_lds16(Kg + (size_t)(j + r) * 4096 + c, &Ks[ci * 8]);
        }
#pragma unroll
        for (int i = 0; i < 2; ++i) {
            const int ci = t + i * 256;
            const int r  = ci >> 3;
            const int c  = ((ci & 7) ^ (r & 7)) * 8;
            gload_lds16(Vg + (size_t)r * 1024 + j + c, &Vs[ci * 8]);
        }
        __syncthreads();

        // S = Q K^T  over head-dim 64 (2 k-chunks of 32)
        floatx4 s_acc[4][2] = {};
#pragma unroll
        for (int kc = 0; kc < 2; ++kc) {
            const int cc = kc * 4 + quad;
            f16x8 af[4], bf[2];
#pragma unroll
            for (int tm = 0; tm < 4; ++tm) {
                const int q = wm + tm * 16 + fr;
                af[tm] = *(const f16x8*)&Qs[(q * 8 + (cc ^ (q & 7))) * 8];
            }
#pragma unroll
            for (int tn = 0; tn < 2; ++tn) {
                const int kv = wn + tn * 16 + fr;
                bf[tn] = *(const f16x8*)&Ks[(kv * 8 + (cc ^ (kv & 7))) * 8];
            }
#pragma unroll
            for (int tm = 0; tm < 4; ++tm)
#pragma unroll
                for (int tn = 0; tn < 2; ++tn)
                    s_acc[tm][tn] = __builtin_amdgcn_mfma_f32_16x16x32_f16(af[tm], bf[tn], s_acc[tm][tn], 0, 0, 0);
        }

        // ×decay, cast f16, write to padded Ss (C/D: row=quad*4+r, col=fr)
#pragma unroll
        for (int tm = 0; tm < 4; ++tm) {
#pragma unroll
            for (int tn = 0; tn < 2; ++tn) {
#pragma unroll
                for (int r = 0; r < 4; ++r) {
                    const int q  = wm + tm * 16 + quad * 4 + r;
                    const int kv = wn + tn * 16 + fr;
                    const float dv = Dg[(size_t)(m0 + q) * 1024 + j + kv];
                    Ss[q * 72 + kv] = (f16)(s_acc[tm][tn][r] * dv);
                }
            }
        }
        __syncthreads();

        // O += S V   over kv 64 (2 k-chunks of 32)
#pragma unroll
        for (int kc = 0; kc < 2; ++kc) {
            const int cc = kc * 4 + quad;
            f16x8 af[4], bf[2];
#pragma unroll
            for (int tm = 0; tm < 4; ++tm) {
                const int q = wm + tm * 16 + fr;
                af[tm] = *(const f16x8*)&Ss[q * 72 + cc * 8];
            }
#pragma unroll
            for (int tn = 0; tn < 2; ++tn) {
                const int d = wn + tn * 16 + fr;
                bf[tn] = *(const f16x8*)&Vs[(d * 8 + (cc ^ (d & 7))) * 8];
            }
#pragma unroll
            for (int tm = 0; tm < 4; ++tm)
#pragma unroll
                for (int tn = 0; tn < 2; ++tn)
                    o_acc[tm][tn] = __builtin_amdgcn_mfma_f32_16x16x32_f16(af[tm], bf[tn], o_acc[tm][tn], 0, 0, 0);
        }
        __syncthreads();   // protect Ks/Vs/Ss before next stage
    }

    // epilogue: o * silu(xo) -> stage in Ss -> coalesced flush
#pragma unroll
    for (int tm = 0; tm < 4; ++tm) {
#pragma unroll
        for (int tn = 0; tn < 2; ++tn) {
#pragma unroll
            for (int r = 0; r < 4; ++r) {
                const int q = wm + tm * 16 + quad * 4 + r;
                const int d = wn + tn * 16 + fr;
                float g = (float)XOg[(size_t)q * 4096 + d];
                g = g * __builtin_amdgcn_rcpf(1.f + __expf(-g));
                Ss[q * 72 + d] = (f16)(o_acc[tm][tn][r] * g);
            }
        }
    }
    __syncthreads();
    f16* Og = gated + (size_t)(b * 1024 + m0) * 1024 + h * 64;
#pragma unroll
    for (int i = 0; i < 4; ++i) {
        const int jj = t + i * 256;         // 1024 chunks: 128 rows x 8
        const int rr = jj >> 3;
        const int cc = jj & 7;
        const uint2 lo = *(const uint2*)&Ss[rr * 72 + cc * 8];
        const uint2 hi = *(const uint2*)&Ss[rr * 72 + cc * 8 + 4];
        uint4 val = make_uint4(lo.x, lo.y, hi.x, hi.y);
        *(uint4*)(Og + (size_t)rr * 1024 + cc * 8) = val;
    }
}

// C[m,n] = sum_k A[m,k] * B[n,k]  ("BT" form). 256 thr = 4 waves, 2x2 grid.
// blockIdx.z packs ((zo*inner + zi)*nsplit + ks); split ks covers K-range
// [ks*Kc,(ks+1)*Kc), partial written at cOff + ks*sCk (EP_PARTIAL_F32).
// K (and Kc) must be multiples of 64.
template <int BM, int BN, int WM, int WN, int EP>
__global__ __launch_bounds__(256, 4) void gemm_bt(
    const f16* __restrict__ A, const f16* __restrict__ B, void* __restrict__ Cv,
    int M, int N, int K, int lda, int ldb, int ldc,
    long long sAo, long long sAi, long long sBo, long long sBi,
    long long sCo, long long sCi, int inner,
    int nsplit, int Kc, long long sCk,
    const float* __restrict__ bias,
    const void* __restrict__ aux, long long sXo, long long sXi, int ldaux)
{
    constexpr bool OUT_F32 = (EP == EP_PARTIAL_F32);
    typedef typename out_sel<OUT_F32>::T OutT;
    constexpr int ESIZE       = OUT_F32 ? 4 : 2;
    constexpr int CSTRIDE     = BN + 4;                  // stage row stride, elems
    constexpr int TILE_BYTES  = (BM + BN) * 64 * 2;      // BK=64 f16 tiles
    constexpr int STAGE_BYTES = BM * CSTRIDE * ESIZE;    // full-tile C stage
    constexpr int SMEM_BYTES  = TILE_BYTES > STAGE_BYTES ? TILE_BYTES : STAGE_BYTES;

    __shared__ __align__(16) char smem[SMEM_BYTES];
    f16*  As = (f16*)smem;
    f16*  Bs = (f16*)(smem + BM * 128);
    OutT* Cs = (OutT*)smem;

    int z = blockIdx.z;
    const int ks = z % nsplit; z /= nsplit;
    const int zo = z / inner, zi = z % inner;
    A += zo * sAo + zi * sAi;
    B += zo * sBo + zi * sBi;
    const long long cOff = (long long)zo * sCo + (long long)zi * sCi + (long long)ks * sCk;
    const long long xOff = (long long)zo * sXo + (long long)zi * sXi;

    const int m0 = blockIdx.y * BM;
    const int n0 = blockIdx.x * BN;

    const int t    = threadIdx.x;
    const int lane = t & 63;
    const int w    = t >> 6;
    const int wm   = (w >> 1) * (WM * 16);
    const int wn   = (w & 1) * (WN * 16);
    const int fr   = lane & 15;          // A/B row within 16-tile
    const int quad = lane >> 4;          // 0..3, k-offset quad*8

    constexpr int ACH = BM / 32;         // 16B chunks per thread for A tile
    constexpr int BCH = BN / 32;

    floatx4 acc[WM][WN] = {};

    const int kbeg = ks * Kc, kend = kbeg + Kc;
    for (int kk = kbeg; kk < kend; kk += 64) {
        // async global->LDS, 16B/lane. LDS layout XOR-swizzled: LDS chunk
        // (r, sc) holds global chunk (r, sc ^ (r&7)); achieved by permuting
        // the global source per lane (dest is forced to base + lane*16).
#pragma unroll
        for (int i = 0; i < ACH; ++i) {
            const int ci = t + i * 256;
            const int r  = ci >> 3;
            const int c  = ((ci & 7) ^ (r & 7)) * 8;
            gload_lds16(A + (size_t)(m0 + r) * lda + kk + c, &As[ci * 8]);
        }
#pragma unroll
        for (int i = 0; i < BCH; ++i) {
            const int ci = t + i * 256;
            const int r  = ci >> 3;
            const int c  = ((ci & 7) ^ (r & 7)) * 8;
            gload_lds16(B + (size_t)(n0 + r) * ldb + kk + c, &Bs[ci * 8]);
        }
        __syncthreads();

#pragma unroll
        for (int kh = 0; kh < 2; ++kh) {
            const int cc = kh * 4 + quad;             // 16B chunk within row
            f16x8 af[WM], bf[WN];
#pragma unroll
            for (int tm = 0; tm < WM; ++tm) {
                const int r = wm + tm * 16 + fr;
                af[tm] = *(const f16x8*)&As[(r * 8 + (cc ^ (r & 7))) * 8];
            }
#pragma unroll
            for (int tn = 0; tn < WN; ++tn) {
                const int r = wn + tn * 16 + fr;
                bf[tn] = *(const f16x8*)&Bs[(r * 8 + (cc ^ (r & 7))) * 8];
            }
#pragma unroll
            for (int tm = 0; tm < WM; ++tm)
#pragma unroll
                for (int tn = 0; tn < WN; ++tn)
                    acc[tm][tn] = __builtin_amdgcn_mfma_f32_16x16x32_f16(af[tm], bf[tn], acc[tm][tn], 0, 0, 0);
        }
        __syncthreads();
    }

    // ---- epilogue: C/D layout col=lane&15, row=(lane>>4)*4+reg [m89] ----
    const int er = quad * 4;
    const int ec = lane & 15;
#pragma unroll
    for (int tm = 0; tm < WM; ++tm) {
#pragma unroll
        for (int tn = 0; tn < WN; ++tn) {
#pragma unroll
            for (int r = 0; r < 4; ++r) {
                const int lrow = wm + tm * 16 + er + r;       // 0..BM-1
                const int col  = wn + tn * 16 + ec;           // 0..BN-1
                const int grow = m0 + lrow;
                const int gcol = n0 + col;
                const float v = acc[tm][tn][r];
                float val;
                if constexpr (EP == EP_BIAS_F16) {
                    val = v + bias[gcol];
                } else if constexpr (EP == EP_DECAY_F16) {
                    const float* dk = (const float*)aux + xOff;
                    val = v * dk[(size_t)grow * ldaux + gcol];
                } else if constexpr (EP == EP_BIAS_GELU_F16) {
                    const float u = v + bias[gcol];
                    val = 0.5f * u * (1.f + erf_fast(u * 0.70710678118f));
                } else {
                    val = v;
                }
                Cs[lrow * CSTRIDE + col] = (OutT)val;
            }
        }
    }
    __syncthreads();

    constexpr int PER_ROW = BN * ESIZE / 16;          // 16B chunks per row
    constexpr int NCHUNK  = (BM * PER_ROW) / 256;     // chunks per thread
#pragma unroll
    for (int i = 0; i < NCHUNK; ++i) {
        const int j  = t + i * 256;
        const int rr = j / PER_ROW;
        const int cc = j - rr * PER_ROW;
        const char* src = smem + (size_t)rr * (CSTRIDE * ESIZE) + (size_t)cc * 16;
        uint4 val;
        if constexpr (OUT_F32) {
            val = *(const uint4*)src;                 // stride 272B: 16B-aligned
        } else {
            const uint2 lo = *(const uint2*)src;      // stride 264B: 8B-aligned
            const uint2 hi = *(const uint2*)(src + 8);
            val = make_uint4(lo.x, lo.y, hi.x, hi.y);
        }
        char* dst = (char*)Cv +
            (size_t)(cOff + (long long)(m0 + rr) * ldc + n0) * ESIZE +
            (size_t)cc * 16;
        *(uint4*)dst = val;
    }
}

// out[4096,1024] = P0 + P1 + bias[col] + res   (all f32, float4 vectorized)
__global__ __launch_bounds__(256) void reduce2_bias_res(
    const float4* __restrict__ P, const float* __restrict__ bias,
    const float4* __restrict__ res, float4* __restrict__ out)
{
    const int i = blockIdx.x * 256 + threadIdx.x;   // 1,048,576 groups
    const int col4 = i & 255;
    const float4 a = P[i];
    const float4 b = P[i + 1048576];
    const float4 r = res[i];
    const float4 bi = ((const float4*)bias)[col4];
    float4 o;
    o.x = a.x + b.x + r.x + bi.x;
    o.y = a.y + b.y + r.y + bi.y;
    o.z = a.z + b.z + r.z + bi.z;
    o.w = a.w + b.w + r.w + bi.w;
    out[i] = o;
}

// LayerNorm over D=1024, one block (256 thr) per row, fp16 output.
__global__ __launch_bounds__(256) void ln_to_f16(
    const float* __restrict__ x, const float* __restrict__ g,
    const float* __restrict__ b, f16* __restrict__ out)
{
    const int row = blockIdx.x;
    const int t = threadIdx.x;
    const float4 xv = ((const float4*)(x + (size_t)row * 1024))[t];
    float s  = xv.x + xv.y + xv.z + xv.w;
    float ss = xv.x * xv.x + xv.y * xv.y + xv.z * xv.z + xv.w * xv.w;
    for (int o = 32; o > 0; o >>= 1) {
        s  += __shfl_down(s, o, 64);
        ss += __shfl_down(ss, o, 64);
    }
    __shared__ float red[8];
    const int wv = t >> 6;
    if ((t & 63) == 0) { red[wv] = s; red[wv + 4] = ss; }
    __syncthreads();
    s  = red[0] + red[1] + red[2] + red[3];
    ss = red[4] + red[5] + red[6] + red[7];
    const float mean = s * (1.f / 1024.f);
    const float var  = ss * (1.f / 1024.f) - mean * mean;
    const float rstd = rsqrtf(var + 1e-5f);
    const float4 gv = ((const float4*)g)[t];
    const float4 bv = ((const float4*)b)[t];
    alignas(8) f16 h[4];
    h[0] = (f16)((xv.x - mean) * rstd * gv.x + bv.x);
    h[1] = (f16)((xv.y - mean) * rstd * gv.y + bv.y);
    h[2] = (f16)((xv.z - mean) * rstd * gv.z + bv.z);
    h[3] = (f16)((xv.w - mean) * rstd * gv.w + bv.w);
    ((uint2*)(out + (size_t)row * 1024))[t] = *(uint2*)h;
}

// f32 -> f16 cast, 4 elems/thread
__global__ __launch_bounds__(256) void cast_f32_f16(
    const float* __restrict__ in, f16* __restrict__ out, int n4)
{
    const int i = blockIdx.x * 256 + threadIdx.x;
    if (i < n4) {
        const float4 v = ((const float4*)in)[i];
        alignas(8) f16 h[4] = {(f16)v.x, (f16)v.y, (f16)v.z, (f16)v.w};
        ((uint2*)out)[i] = *(uint2*)h;
    }
}

// vT[z=(b*16+h)][d][m] = p[b*1024+m][2048 + h*64 + d]   (64x64 LDS tile)
__global__ __launch_bounds__(256) void transpose_v(
    const f16* __restrict__ p, f16* __restrict__ vT)
{
    const int z = blockIdx.y;
    const int b = z >> 4, h = z & 15;
    const int m0 = blockIdx.x * 64;
    __shared__ f16 tile[64][72];
    const int t = threadIdx.x;
    const f16* src = p + (size_t)(b * 1024 + m0) * 4096 + 2048 + h * 64;
#pragma unroll
    for (int pass = 0; pass < 4; ++pass) {
        const int r = (t >> 4) + pass * 16;   // m
        const int c = (t & 15) * 4;           // d
        *(uint2*)&tile[r][c] = *(const uint2*)(src + (size_t)r * 4096 + c);
    }
    __syncthreads();
    f16* dst = vT + (size_t)z * 65536 + m0;
#pragma unroll
    for (int pass = 0; pass < 4; ++pass) {
        const int d  = (t >> 4) + pass * 16;
        const int mc = (t & 15) * 4;
        alignas(8) f16 tmp[4] = {tile[mc][d], tile[mc + 1][d], tile[mc + 2][d], tile[mc + 3][d]};
        *(uint2*)(dst + (size_t)d * 1024 + mc) = *(uint2*)tmp;
    }
}

extern "C" void kernel_launch(void* const* d_in, const int* in_sizes, int n_in,
                              void* d_out, int out_size, void* d_ws, size_t ws_size,
                              hipStream_t stream) {
    const float* x      = (const float*)d_in[0];
    const float* decay  = (const float*)d_in[1];
    const float* ln1_g  = (const float*)d_in[2];
    const float* ln1_b  = (const float*)d_in[3];
    const float* proj_W = (const float*)d_in[4];
    const float* proj_b = (const float*)d_in[5];
    const float* reto_W = (const float*)d_in[6];
    const float* reto_b = (const float*)d_in[7];
    const float* ln2_g  = (const float*)d_in[8];
    const float* ln2_b  = (const float*)d_in[9];
    const float* ffn1_W = (const float*)d_in[10];
    const float* ffn1_b = (const float*)d_in[11];
    const float* ffn2_W = (const float*)d_in[12];
    const float* ffn2_b = (const float*)d_in[13];
    float* out = (float*)d_out;

    // Workspace (114 MB, liveness-aliased):
    //   Wp 8MB [cast..G1] -> gated [attn..G4]
    //   Wr 2MB, W1 8MB, W2 8MB
    //   buf8 8MB: lnx[LN1..G1] -> vT[transp..attn] -> hln[LN2..G5]
    //   p 32MB [G1..attn(xo)] -> ffh [G5..G6]
    //   S 32MB: G4/G6 splitK partials (2x16MB)
    //   y 16MB [G4red..G6]
    char* w = (char*)d_ws;
    auto alloc = [&](size_t bytes) { char* r = w; w += (bytes + 255) & ~(size_t)255; return r; };
    f16*   Wp   = (f16*)alloc((size_t)4096 * 1024 * 2);
    f16*   Wr   = (f16*)alloc((size_t)1024 * 1024 * 2);
    f16*   W1   = (f16*)alloc((size_t)4096 * 1024 * 2);
    f16*   W2   = (f16*)alloc((size_t)1024 * 4096 * 2);
    f16*   buf8 = (f16*)alloc((size_t)4096 * 1024 * 2);
    f16*   p    = (f16*)alloc((size_t)4096 * 4096 * 2);
    f16*   S    = (f16*)alloc((size_t)16 * 1024 * 1024 * 2);
    float* y    = (float*)alloc((size_t)4096 * 1024 * 4);

    f16*   lnx   = buf8;
    f16*   vT    = buf8;
    f16*   hln   = buf8;
    f16*   gated = Wp;
    f16*   ffh   = p;
    float* Pk    = (float*)S;   // split-K partials for G4/G6 (2 x 16MB)

    // weight casts
    cast_f32_f16<<<4096, 256, 0, stream>>>(proj_W, Wp, 1048576);
    cast_f32_f16<<<1024, 256, 0, stream>>>(reto_W, Wr, 262144);
    cast_f32_f16<<<4096, 256, 0, stream>>>(ffn1_W, W1, 1048576);
    cast_f32_f16<<<4096, 256, 0, stream>>>(ffn2_W, W2, 1048576);

    // LN1
    ln_to_f16<<<4096, 256, 0, stream>>>(x, ln1_g, ln1_b, lnx);

    // G1: p = lnx @ proj_W^T + proj_b     [4096,4096] K=1024
    gemm_bt<128, 128, 4, 4, EP_BIAS_F16><<<dim3(32, 32, 1), 256, 0, stream>>>(
        lnx, Wp, p, 4096, 4096, 1024, 1024, 1024, 4096,
        0, 0, 0, 0, 0, 0, 1, 1, 1024, 0, proj_b, nullptr, 0, 0, 0);

    // v transpose (overwrites lnx, dead after G1)
    transpose_v<<<dim3(16, 64), 256, 0, stream>>>(p, vT);

    // fused attention: gated = (QK^T * decay) V * silu(xo)
    attn_fused<<<dim3(8, 64), 256, 0, stream>>>(p, vT, decay, gated);

    // G4: Pk = gated @ reto_W^T  (split-K=2, Kc=512) -> y = +reto_b + x
    gemm_bt<128, 64, 4, 2, EP_PARTIAL_F32><<<dim3(16, 32, 2), 256, 0, stream>>>(
        gated, Wr, Pk, 4096, 1024, 1024, 1024, 1024, 1024,
        0, 0, 0, 0, 0, 0, 1, 2, 512, 4194304, nullptr, nullptr, 0, 0, 0);
    reduce2_bias_res<<<4096, 256, 0, stream>>>(
        (const float4*)Pk, reto_b, (const float4*)x, (float4*)y);

    // LN2
    ln_to_f16<<<4096, 256, 0, stream>>>(y, ln2_g, ln2_b, hln);

    // G5: ffh = gelu(hln @ ffn1_W^T + ffn1_b)   [4096,4096] K=1024
    gemm_bt<128, 128, 4, 4, EP_BIAS_GELU_F16><<<dim3(32, 32, 1), 256, 0, stream>>>(
        hln, W1, ffh, 4096, 4096, 1024, 1024, 1024, 4096,
        0, 0, 0, 0, 0, 0, 1, 1, 1024, 0, ffn1_b, nullptr, 0, 0, 0);

    // G6: Pk = ffh @ ffn2_W^T (split-K=2, Kc=2048) -> out = +ffn2_b + y
    gemm_bt<128, 64, 4, 2, EP_PARTIAL_F32><<<dim3(16, 32, 2), 256, 0, stream>>>(
        ffh, W2, Pk, 4096, 1024, 4096, 4096, 4096, 1024,
        0, 0, 0, 0, 0, 0, 1, 2, 2048, 4194304, nullptr, nullptr, 0, 0, 0);
    reduce2_bias_res<<<4096, 256, 0, stream>>>(
        (const float4*)Pk, ffn2_b, (const float4*)y, (float4*)out);
}

// Round 7
// 411.956 us; speedup vs baseline: 1.2537x; 1.2537x over previous
//
#include <hip/hip_runtime.h>

// ---------------------------------------------------------------------------
// RetnetBlock fp16-MFMA implementation.
// R6: attn_fused v2 — R5's fused kernel was latency-bound (Mfma 4%, HBM 9%,
//     2 blocks/CU, decay loads serialized in their own barrier segment).
//     Fix: BM=64 (1024 blocks, 4/CU, 16 waves/CU) + decay prefetched into
//     VGPRs at iteration top so its latency overlaps the async K/V staging
//     (both drain at the same barrier). gemm_bt core unchanged from R4.
// ---------------------------------------------------------------------------

typedef _Float16 f16;
typedef _Float16 f16x8 __attribute__((ext_vector_type(8)));
typedef float floatx4 __attribute__((ext_vector_type(4)));

#define EP_BIAS_F16      0
#define EP_DECAY_F16     1
#define EP_BIAS_GELU_F16 2
#define EP_PARTIAL_F32   3

template <bool F32> struct out_sel { typedef f16 T; };
template <> struct out_sel<true>   { typedef float T; };

__device__ __forceinline__ void gload_lds16(const void* g, void* s) {
    __builtin_amdgcn_global_load_lds(
        (const __attribute__((address_space(1))) unsigned int*)g,
        (__attribute__((address_space(3))) unsigned int*)s, 16, 0, 0);
}

// erf via Abramowitz-Stegun 7.1.26, |abs err| <= 1.5e-7
__device__ __forceinline__ float erf_fast(float x) {
    const float ax = fabsf(x);
    const float t  = __builtin_amdgcn_rcpf(1.f + 0.3275911f * ax);
    const float p  = t * (0.254829592f + t * (-0.284496736f + t * (1.421413741f +
                     t * (-1.453152027f + t * 1.061405429f))));
    const float r  = 1.f - p * __expf(-ax * ax);
    return copysignf(r, x);
}

// ---------------------------------------------------------------------------
// Fused attention: gated[b*1024+l, h*64+d] =
//   (sum_m (q_l . k_m) * decay[h,l,m] * v_m_d) * silu(xo[l, h*64+d])
// Block = 64 Q-rows x one (b,h); 4 waves in 2x2 (wave tile 32x32).
// KV tiles of 64. Decay prefetched to VGPRs concurrent with K/V staging.
// ---------------------------------------------------------------------------
__global__ __launch_bounds__(256, 4) void attn_fused(
    const f16* __restrict__ p, const f16* __restrict__ vT,
    const float* __restrict__ decay, f16* __restrict__ gated)
{
    const int z = blockIdx.y;
    const int b = z >> 4, h = z & 15;
    const int m0 = blockIdx.x * 64;

    __shared__ __align__(16) f16 Qs[64 * 64];    // 8 KB, swizzled chunks
    __shared__ __align__(16) f16 Ks[64 * 64];    // 8 KB, swizzled
    __shared__ __align__(16) f16 Vs[64 * 64];    // 8 KB, swizzled
    __shared__ __align__(16) f16 Ss[64 * 72];    // 9 KB, padded (+8/row)

    const int t    = threadIdx.x;
    const int lane = t & 63;
    const int w    = t >> 6;
    const int quad = lane >> 4;
    const int fr   = lane & 15;
    const int wm   = (w >> 1) * 32;   // q-offset of wave
    const int wn   = (w & 1) * 32;    // kv-offset (S phase) / d-offset (PV)

    const f16*   Qg  = p + (size_t)(b * 1024 + m0) * 4096 + h * 64;
    const f16*   Kg  = p + (size_t)(b * 1024) * 4096 + 1024 + h * 64;
    const f16*   Vg  = vT + (size_t)z * 65536;                     // [64][1024]
    const float* Dg  = decay + (size_t)h * 1048576 + (size_t)m0 * 1024;
    const f16*   XOg = p + (size_t)(b * 1024 + m0) * 4096 + 3072 + h * 64;

    // stage Q (64 rows x 64 f16 = 512 16B-chunks), XOR-swizzled
#pragma unroll
    for (int i = 0; i < 2; ++i) {
        const int ci = t + i * 256;
        const int r  = ci >> 3;
        const int c  = ((ci & 7) ^ (r & 7)) * 8;
        gload_lds16(Qg + (size_t)r * 4096 + c, &Qs[ci * 8]);
    }

    floatx4 o_acc[2][2] = {};

    for (int j = 0; j < 1024; j += 64) {
        // decay prefetch (VGPRs) — issued alongside the staging loads below,
        // so its latency overlaps the K/V DMA and drains at the same barrier.
        float dreg[2][2][4];
#pragma unroll
        for (int tm = 0; tm < 2; ++tm)
#pragma unroll
            for (int tn = 0; tn < 2; ++tn)
#pragma unroll
                for (int r = 0; r < 4; ++r)
                    dreg[tm][tn][r] = Dg[(size_t)(wm + tm * 16 + quad * 4 + r) * 1024
                                          + j + wn + tn * 16 + fr];
        // stage K,V tiles (64x64 each = 512 chunks each)
#pragma unroll
        for (int i = 0; i < 2; ++i) {
            const int ci = t + i * 256;
            const int r  = ci >> 3;
            const int c  = ((ci & 7) ^ (r & 7)) * 8;
            gload_lds16(Kg + (size_t)(j + r) * 4096 + c, &Ks[ci * 8]);
        }
#pragma unroll
        for (int i = 0; i < 2; ++i) {
            const int ci = t + i * 256;
            const int r  = ci >> 3;
            const int c  = ((ci & 7) ^ (r & 7)) * 8;
            gload_lds16(Vg + (size_t)r * 1024 + j + c, &Vs[ci * 8]);
        }
        __syncthreads();

        // S = Q K^T  over head-dim 64 (2 k-chunks of 32)
        floatx4 s_acc[2][2] = {};
#pragma unroll
        for (int kc = 0; kc < 2; ++kc) {
            const int cc = kc * 4 + quad;
            f16x8 af[2], bf[2];
#pragma unroll
            for (int tm = 0; tm < 2; ++tm) {
                const int q = wm + tm * 16 + fr;
                af[tm] = *(const f16x8*)&Qs[(q * 8 + (cc ^ (q & 7))) * 8];
            }
#pragma unroll
            for (int tn = 0; tn < 2; ++tn) {
                const int kv = wn + tn * 16 + fr;
                bf[tn] = *(const f16x8*)&Ks[(kv * 8 + (cc ^ (kv & 7))) * 8];
            }
#pragma unroll
            for (int tm = 0; tm < 2; ++tm)
#pragma unroll
                for (int tn = 0; tn < 2; ++tn)
                    s_acc[tm][tn] = __builtin_amdgcn_mfma_f32_16x16x32_f16(af[tm], bf[tn], s_acc[tm][tn], 0, 0, 0);
        }

        // ×decay (registers), cast f16, write padded Ss (C/D row=quad*4+r)
#pragma unroll
        for (int tm = 0; tm < 2; ++tm)
#pragma unroll
            for (int tn = 0; tn < 2; ++tn)
#pragma unroll
                for (int r = 0; r < 4; ++r) {
                    const int q  = wm + tm * 16 + quad * 4 + r;
                    const int kv = wn + tn * 16 + fr;
                    Ss[q * 72 + kv] = (f16)(s_acc[tm][tn][r] * dreg[tm][tn][r]);
                }
        __syncthreads();

        // O += S V   over kv 64 (2 k-chunks of 32)
#pragma unroll
        for (int kc = 0; kc < 2; ++kc) {
            const int cc = kc * 4 + quad;
            f16x8 af[2], bf[2];
#pragma unroll
            for (int tm = 0; tm < 2; ++tm) {
                const int q = wm + tm * 16 + fr;
                af[tm] = *(const f16x8*)&Ss[q * 72 + cc * 8];
            }
#pragma unroll
            for (int tn = 0; tn < 2; ++tn) {
                const int d = wn + tn * 16 + fr;
                bf[tn] = *(const f16x8*)&Vs[(d * 8 + (cc ^ (d & 7))) * 8];
            }
#pragma unroll
            for (int tm = 0; tm < 2; ++tm)
#pragma unroll
                for (int tn = 0; tn < 2; ++tn)
                    o_acc[tm][tn] = __builtin_amdgcn_mfma_f32_16x16x32_f16(af[tm], bf[tn], o_acc[tm][tn], 0, 0, 0);
        }
        __syncthreads();   // protect Ks/Vs/Ss before next stage
    }

    // epilogue: o * silu(xo) -> stage in Ss -> coalesced flush
#pragma unroll
    for (int tm = 0; tm < 2; ++tm)
#pragma unroll
        for (int tn = 0; tn < 2; ++tn)
#pragma unroll
            for (int r = 0; r < 4; ++r) {
                const int q = wm + tm * 16 + quad * 4 + r;
                const int d = wn + tn * 16 + fr;
                float g = (float)XOg[(size_t)q * 4096 + d];
                g = g * __builtin_amdgcn_rcpf(1.f + __expf(-g));
                Ss[q * 72 + d] = (f16)(o_acc[tm][tn][r] * g);
            }
    __syncthreads();
    f16* Og = gated + (size_t)(b * 1024 + m0) * 1024 + h * 64;
#pragma unroll
    for (int i = 0; i < 2; ++i) {
        const int jj = t + i * 256;         // 512 chunks: 64 rows x 8
        const int rr = jj >> 3;
        const int cc = jj & 7;
        const uint2 lo = *(const uint2*)&Ss[rr * 72 + cc * 8];
        const uint2 hi = *(const uint2*)&Ss[rr * 72 + cc * 8 + 4];
        uint4 val = make_uint4(lo.x, lo.y, hi.x, hi.y);
        *(uint4*)(Og + (size_t)rr * 1024 + cc * 8) = val;
    }
}

// C[m,n] = sum_k A[m,k] * B[n,k]  ("BT" form). 256 thr = 4 waves, 2x2 grid.
// blockIdx.z packs ((zo*inner + zi)*nsplit + ks); split ks covers K-range
// [ks*Kc,(ks+1)*Kc), partial written at cOff + ks*sCk (EP_PARTIAL_F32).
// K (and Kc) must be multiples of 64.
template <int BM, int BN, int WM, int WN, int EP>
__global__ __launch_bounds__(256, 4) void gemm_bt(
    const f16* __restrict__ A, const f16* __restrict__ B, void* __restrict__ Cv,
    int M, int N, int K, int lda, int ldb, int ldc,
    long long sAo, long long sAi, long long sBo, long long sBi,
    long long sCo, long long sCi, int inner,
    int nsplit, int Kc, long long sCk,
    const float* __restrict__ bias,
    const void* __restrict__ aux, long long sXo, long long sXi, int ldaux)
{
    constexpr bool OUT_F32 = (EP == EP_PARTIAL_F32);
    typedef typename out_sel<OUT_F32>::T OutT;
    constexpr int ESIZE       = OUT_F32 ? 4 : 2;
    constexpr int CSTRIDE     = BN + 4;                  // stage row stride, elems
    constexpr int TILE_BYTES  = (BM + BN) * 64 * 2;      // BK=64 f16 tiles
    constexpr int STAGE_BYTES = BM * CSTRIDE * ESIZE;    // full-tile C stage
    constexpr int SMEM_BYTES  = TILE_BYTES > STAGE_BYTES ? TILE_BYTES : STAGE_BYTES;

    __shared__ __align__(16) char smem[SMEM_BYTES];
    f16*  As = (f16*)smem;
    f16*  Bs = (f16*)(smem + BM * 128);
    OutT* Cs = (OutT*)smem;

    int z = blockIdx.z;
    const int ks = z % nsplit; z /= nsplit;
    const int zo = z / inner, zi = z % inner;
    A += zo * sAo + zi * sAi;
    B += zo * sBo + zi * sBi;
    const long long cOff = (long long)zo * sCo + (long long)zi * sCi + (long long)ks * sCk;
    const long long xOff = (long long)zo * sXo + (long long)zi * sXi;

    const int m0 = blockIdx.y * BM;
    const int n0 = blockIdx.x * BN;

    const int t    = threadIdx.x;
    const int lane = t & 63;
    const int w    = t >> 6;
    const int wm   = (w >> 1) * (WM * 16);
    const int wn   = (w & 1) * (WN * 16);
    const int fr   = lane & 15;          // A/B row within 16-tile
    const int quad = lane >> 4;          // 0..3, k-offset quad*8

    constexpr int ACH = BM / 32;         // 16B chunks per thread for A tile
    constexpr int BCH = BN / 32;

    floatx4 acc[WM][WN] = {};

    const int kbeg = ks * Kc, kend = kbeg + Kc;
    for (int kk = kbeg; kk < kend; kk += 64) {
        // async global->LDS, 16B/lane. LDS layout XOR-swizzled: LDS chunk
        // (r, sc) holds global chunk (r, sc ^ (r&7)).
#pragma unroll
        for (int i = 0; i < ACH; ++i) {
            const int ci = t + i * 256;
            const int r  = ci >> 3;
            const int c  = ((ci & 7) ^ (r & 7)) * 8;
            gload_lds16(A + (size_t)(m0 + r) * lda + kk + c, &As[ci * 8]);
        }
#pragma unroll
        for (int i = 0; i < BCH; ++i) {
            const int ci = t + i * 256;
            const int r  = ci >> 3;
            const int c  = ((ci & 7) ^ (r & 7)) * 8;
            gload_lds16(B + (size_t)(n0 + r) * ldb + kk + c, &Bs[ci * 8]);
        }
        __syncthreads();

#pragma unroll
        for (int kh = 0; kh < 2; ++kh) {
            const int cc = kh * 4 + quad;             // 16B chunk within row
            f16x8 af[WM], bf[WN];
#pragma unroll
            for (int tm = 0; tm < WM; ++tm) {
                const int r = wm + tm * 16 + fr;
                af[tm] = *(const f16x8*)&As[(r * 8 + (cc ^ (r & 7))) * 8];
            }
#pragma unroll
            for (int tn = 0; tn < WN; ++tn) {
                const int r = wn + tn * 16 + fr;
                bf[tn] = *(const f16x8*)&Bs[(r * 8 + (cc ^ (r & 7))) * 8];
            }
#pragma unroll
            for (int tm = 0; tm < WM; ++tm)
#pragma unroll
                for (int tn = 0; tn < WN; ++tn)
                    acc[tm][tn] = __builtin_amdgcn_mfma_f32_16x16x32_f16(af[tm], bf[tn], acc[tm][tn], 0, 0, 0);
        }
        __syncthreads();
    }

    // ---- epilogue: C/D layout col=lane&15, row=(lane>>4)*4+reg [m89] ----
    const int er = quad * 4;
    const int ec = lane & 15;
#pragma unroll
    for (int tm = 0; tm < WM; ++tm) {
#pragma unroll
        for (int tn = 0; tn < WN; ++tn) {
#pragma unroll
            for (int r = 0; r < 4; ++r) {
                const int lrow = wm + tm * 16 + er + r;       // 0..BM-1
                const int col  = wn + tn * 16 + ec;           // 0..BN-1
                const int grow = m0 + lrow;
                const int gcol = n0 + col;
                const float v = acc[tm][tn][r];
                float val;
                if constexpr (EP == EP_BIAS_F16) {
                    val = v + bias[gcol];
                } else if constexpr (EP == EP_DECAY_F16) {
                    const float* dk = (const float*)aux + xOff;
                    val = v * dk[(size_t)grow * ldaux + gcol];
                } else if constexpr (EP == EP_BIAS_GELU_F16) {
                    const float u = v + bias[gcol];
                    val = 0.5f * u * (1.f + erf_fast(u * 0.70710678118f));
                } else {
                    val = v;
                }
                Cs[lrow * CSTRIDE + col] = (OutT)val;
            }
        }
    }
    __syncthreads();

    constexpr int PER_ROW = BN * ESIZE / 16;          // 16B chunks per row
    constexpr int NCHUNK  = (BM * PER_ROW) / 256;     // chunks per thread
#pragma unroll
    for (int i = 0; i < NCHUNK; ++i) {
        const int j  = t + i * 256;
        const int rr = j / PER_ROW;
        const int cc = j - rr * PER_ROW;
        const char* src = smem + (size_t)rr * (CSTRIDE * ESIZE) + (size_t)cc * 16;
        uint4 val;
        if constexpr (OUT_F32) {
            val = *(const uint4*)src;                 // stride 272B: 16B-aligned
        } else {
            const uint2 lo = *(const uint2*)src;      // stride 264B: 8B-aligned
            const uint2 hi = *(const uint2*)(src + 8);
            val = make_uint4(lo.x, lo.y, hi.x, hi.y);
        }
        char* dst = (char*)Cv +
            (size_t)(cOff + (long long)(m0 + rr) * ldc + n0) * ESIZE +
            (size_t)cc * 16;
        *(uint4*)dst = val;
    }
}

// out[4096,1024] = P0 + P1 + bias[col] + res   (all f32, float4 vectorized)
__global__ __launch_bounds__(256) void reduce2_bias_res(
    const float4* __restrict__ P, const float* __restrict__ bias,
    const float4* __restrict__ res, float4* __restrict__ out)
{
    const int i = blockIdx.x * 256 + threadIdx.x;   // 1,048,576 groups
    const int col4 = i & 255;
    const float4 a = P[i];
    const float4 b = P[i + 1048576];
    const float4 r = res[i];
    const float4 bi = ((const float4*)bias)[col4];
    float4 o;
    o.x = a.x + b.x + r.x + bi.x;
    o.y = a.y + b.y + r.y + bi.y;
    o.z = a.z + b.z + r.z + bi.z;
    o.w = a.w + b.w + r.w + bi.w;
    out[i] = o;
}

// LayerNorm over D=1024, one block (256 thr) per row, fp16 output.
__global__ __launch_bounds__(256) void ln_to_f16(
    const float* __restrict__ x, const float* __restrict__ g,
    const float* __restrict__ b, f16* __restrict__ out)
{
    const int row = blockIdx.x;
    const int t = threadIdx.x;
    const float4 xv = ((const float4*)(x + (size_t)row * 1024))[t];
    float s  = xv.x + xv.y + xv.z + xv.w;
    float ss = xv.x * xv.x + xv.y * xv.y + xv.z * xv.z + xv.w * xv.w;
    for (int o = 32; o > 0; o >>= 1) {
        s  += __shfl_down(s, o, 64);
        ss += __shfl_down(ss, o, 64);
    }
    __shared__ float red[8];
    const int wv = t >> 6;
    if ((t & 63) == 0) { red[wv] = s; red[wv + 4] = ss; }
    __syncthreads();
    s  = red[0] + red[1] + red[2] + red[3];
    ss = red[4] + red[5] + red[6] + red[7];
    const float mean = s * (1.f / 1024.f);
    const float var  = ss * (1.f / 1024.f) - mean * mean;
    const float rstd = rsqrtf(var + 1e-5f);
    const float4 gv = ((const float4*)g)[t];
    const float4 bv = ((const float4*)b)[t];
    alignas(8) f16 h[4];
    h[0] = (f16)((xv.x - mean) * rstd * gv.x + bv.x);
    h[1] = (f16)((xv.y - mean) * rstd * gv.y + bv.y);
    h[2] = (f16)((xv.z - mean) * rstd * gv.z + bv.z);
    h[3] = (f16)((xv.w - mean) * rstd * gv.w + bv.w);
    ((uint2*)(out + (size_t)row * 1024))[t] = *(uint2*)h;
}

// f32 -> f16 cast, 4 elems/thread
__global__ __launch_bounds__(256) void cast_f32_f16(
    const float* __restrict__ in, f16* __restrict__ out, int n4)
{
    const int i = blockIdx.x * 256 + threadIdx.x;
    if (i < n4) {
        const float4 v = ((const float4*)in)[i];
        alignas(8) f16 h[4] = {(f16)v.x, (f16)v.y, (f16)v.z, (f16)v.w};
        ((uint2*)out)[i] = *(uint2*)h;
    }
}

// vT[z=(b*16+h)][d][m] = p[b*1024+m][2048 + h*64 + d]   (64x64 LDS tile)
__global__ __launch_bounds__(256) void transpose_v(
    const f16* __restrict__ p, f16* __restrict__ vT)
{
    const int z = blockIdx.y;
    const int b = z >> 4, h = z & 15;
    const int m0 = blockIdx.x * 64;
    __shared__ f16 tile[64][72];
    const int t = threadIdx.x;
    const f16* src = p + (size_t)(b * 1024 + m0) * 4096 + 2048 + h * 64;
#pragma unroll
    for (int pass = 0; pass < 4; ++pass) {
        const int r = (t >> 4) + pass * 16;   // m
        const int c = (t & 15) * 4;           // d
        *(uint2*)&tile[r][c] = *(const uint2*)(src + (size_t)r * 4096 + c);
    }
    __syncthreads();
    f16* dst = vT + (size_t)z * 65536 + m0;
#pragma unroll
    for (int pass = 0; pass < 4; ++pass) {
        const int d  = (t >> 4) + pass * 16;
        const int mc = (t & 15) * 4;
        alignas(8) f16 tmp[4] = {tile[mc][d], tile[mc + 1][d], tile[mc + 2][d], tile[mc + 3][d]};
        *(uint2*)(dst + (size_t)d * 1024 + mc) = *(uint2*)tmp;
    }
}

extern "C" void kernel_launch(void* const* d_in, const int* in_sizes, int n_in,
                              void* d_out, int out_size, void* d_ws, size_t ws_size,
                              hipStream_t stream) {
    const float* x      = (const float*)d_in[0];
    const float* decay  = (const float*)d_in[1];
    const float* ln1_g  = (const float*)d_in[2];
    const float* ln1_b  = (const float*)d_in[3];
    const float* proj_W = (const float*)d_in[4];
    const float* proj_b = (const float*)d_in[5];
    const float* reto_W = (const float*)d_in[6];
    const float* reto_b = (const float*)d_in[7];
    const float* ln2_g  = (const float*)d_in[8];
    const float* ln2_b  = (const float*)d_in[9];
    const float* ffn1_W = (const float*)d_in[10];
    const float* ffn1_b = (const float*)d_in[11];
    const float* ffn2_W = (const float*)d_in[12];
    const float* ffn2_b = (const float*)d_in[13];
    float* out = (float*)d_out;

    // Workspace (114 MB, liveness-aliased):
    //   Wp 8MB [cast..G1] -> gated [attn..G4]
    //   Wr 2MB, W1 8MB, W2 8MB
    //   buf8 8MB: lnx[LN1..G1] -> vT[transp..attn] -> hln[LN2..G5]
    //   p 32MB [G1..attn(xo)] -> ffh [G5..G6]
    //   S 32MB: G4/G6 splitK partials (2x16MB)
    //   y 16MB [G4red..G6]
    char* w = (char*)d_ws;
    auto alloc = [&](size_t bytes) { char* r = w; w += (bytes + 255) & ~(size_t)255; return r; };
    f16*   Wp   = (f16*)alloc((size_t)4096 * 1024 * 2);
    f16*   Wr   = (f16*)alloc((size_t)1024 * 1024 * 2);
    f16*   W1   = (f16*)alloc((size_t)4096 * 1024 * 2);
    f16*   W2   = (f16*)alloc((size_t)1024 * 4096 * 2);
    f16*   buf8 = (f16*)alloc((size_t)4096 * 1024 * 2);
    f16*   p    = (f16*)alloc((size_t)4096 * 4096 * 2);
    f16*   S    = (f16*)alloc((size_t)16 * 1024 * 1024 * 2);
    float* y    = (float*)alloc((size_t)4096 * 1024 * 4);

    f16*   lnx   = buf8;
    f16*   vT    = buf8;
    f16*   hln   = buf8;
    f16*   gated = Wp;
    f16*   ffh   = p;
    float* Pk    = (float*)S;   // split-K partials for G4/G6 (2 x 16MB)

    // weight casts
    cast_f32_f16<<<4096, 256, 0, stream>>>(proj_W, Wp, 1048576);
    cast_f32_f16<<<1024, 256, 0, stream>>>(reto_W, Wr, 262144);
    cast_f32_f16<<<4096, 256, 0, stream>>>(ffn1_W, W1, 1048576);
    cast_f32_f16<<<4096, 256, 0, stream>>>(ffn2_W, W2, 1048576);

    // LN1
    ln_to_f16<<<4096, 256, 0, stream>>>(x, ln1_g, ln1_b, lnx);

    // G1: p = lnx @ proj_W^T + proj_b     [4096,4096] K=1024
    gemm_bt<128, 128, 4, 4, EP_BIAS_F16><<<dim3(32, 32, 1), 256, 0, stream>>>(
        lnx, Wp, p, 4096, 4096, 1024, 1024, 1024, 4096,
        0, 0, 0, 0, 0, 0, 1, 1, 1024, 0, proj_b, nullptr, 0, 0, 0);

    // v transpose (overwrites lnx, dead after G1)
    transpose_v<<<dim3(16, 64), 256, 0, stream>>>(p, vT);

    // fused attention: gated = (QK^T * decay) V * silu(xo)
    attn_fused<<<dim3(16, 64), 256, 0, stream>>>(p, vT, decay, gated);

    // G4: Pk = gated @ reto_W^T  (split-K=2, Kc=512) -> y = +reto_b + x
    gemm_bt<128, 64, 4, 2, EP_PARTIAL_F32><<<dim3(16, 32, 2), 256, 0, stream>>>(
        gated, Wr, Pk, 4096, 1024, 1024, 1024, 1024, 1024,
        0, 0, 0, 0, 0, 0, 1, 2, 512, 4194304, nullptr, nullptr, 0, 0, 0);
    reduce2_bias_res<<<4096, 256, 0, stream>>>(
        (const float4*)Pk, reto_b, (const float4*)x, (float4*)y);

    // LN2
    ln_to_f16<<<4096, 256, 0, stream>>>(y, ln2_g, ln2_b, hln);

    // G5: ffh = gelu(hln @ ffn1_W^T + ffn1_b)   [4096,4096] K=1024
    gemm_bt<128, 128, 4, 4, EP_BIAS_GELU_F16><<<dim3(32, 32, 1), 256, 0, stream>>>(
        hln, W1, ffh, 4096, 4096, 1024, 1024, 1024, 4096,
        0, 0, 0, 0, 0, 0, 1, 1, 1024, 0, ffn1_b, nullptr, 0, 0, 0);

    // G6: Pk = ffh @ ffn2_W^T (split-K=2, Kc=2048) -> out = +ffn2_b + y
    gemm_bt<128, 64, 4, 2, EP_PARTIAL_F32><<<dim3(16, 32, 2), 256, 0, stream>>>(
        ffh, W2, Pk, 4096, 1024, 4096, 4096, 4096, 1024,
        0, 0, 0, 0, 0, 0, 1, 2, 2048, 4194304, nullptr, nullptr, 0, 0, 0);
    reduce2_bias_res<<<4096, 256, 0, stream>>>(
        (const float4*)Pk, ffn2_b, (const float4*)y, (float4*)out);
}